// Round 7
// baseline (963.916 us; speedup 1.0000x reference)
//
#include <hip/hip_runtime.h>

#define N_NODES 100000
#define N_EDGES 3200000

// CSR binning geometry
#define BSH 8                      // 256 nodes per bucket
#define NB 391                     // ceil(100000/256)
#define NSLOT 8                    // per-XCD write slots
#define G_BIN 2048                 // k_bin grid (multiple of 8)
#define EPB 1563                   // ceil(N_EDGES / G_BIN)

// ======================= CSR build (two-phase binned) =======================

__global__ void k_zero_int(int* __restrict__ p, int n) {
    int i = blockIdx.x * blockDim.x + threadIdx.x;
    if (i < n) p[i] = 0;
}

// histogram into (bucket, slot); slot = static fn of edge index (matches k_bin)
__global__ void k_hist2(const int* __restrict__ ei, int* __restrict__ cnt2, int e) {
    int i4 = (blockIdx.x * blockDim.x + threadIdx.x) * 4;
    if (i4 + 3 < e) {
        int4 d4 = *(const int4*)(ei + e + i4);
        int dd[4] = {d4.x, d4.y, d4.z, d4.w};
#pragma unroll
        for (int j = 0; j < 4; ++j) {
            int i = i4 + j;
            int d = dd[j];
            if ((unsigned)d < (unsigned)N_NODES) {
                int slot = (i / EPB) & (NSLOT - 1);
                atomicAdd(&cnt2[((d >> BSH) * NSLOT) + slot], 1);
            }
        }
    } else {
        for (int i = i4; i < e; ++i) {
            int d = ei[e + i];
            if ((unsigned)d < (unsigned)N_NODES) {
                int slot = (i / EPB) & (NSLOT - 1);
                atomicAdd(&cnt2[((d >> BSH) * NSLOT) + slot], 1);
            }
        }
    }
}

// single-block exclusive scan of NB*NSLOT=3128 counts -> sbase, scur
__global__ void k_scan3k(const int* __restrict__ cnt2, int* __restrict__ sbase,
                         int* __restrict__ scur, int e) {
    constexpr int M = NB * NSLOT;  // 3128
    __shared__ int part[1024];
    int t = (int)threadIdx.x;
    int v[4];
    int s = 0;
#pragma unroll
    for (int j = 0; j < 4; ++j) {
        int idx = t * 4 + j;
        v[j] = (idx < M) ? cnt2[idx] : 0;
        s += v[j];
    }
    part[t] = s;
    __syncthreads();
    for (int off = 1; off < 1024; off <<= 1) {
        int x = (t >= off) ? part[t - off] : 0;
        __syncthreads();
        part[t] += x;
        __syncthreads();
    }
    int run = part[t] - s;  // exclusive base for this thread's 4 values
#pragma unroll
    for (int j = 0; j < 4; ++j) {
        int idx = t * 4 + j;
        if (idx < M) { sbase[idx] = run; scur[idx] = run; }
        run += v[j];
    }
    if (t == 0) sbase[M] = e;
}

// append packed (dst_low<<17 | src) into (bucket, slot=blk&7) regions
__global__ void k_bin(const int* __restrict__ ei, int* __restrict__ scur,
                      unsigned* __restrict__ bins, int e) {
    int g = (int)blockIdx.x;
    int slot = g & (NSLOT - 1);
    int i0 = g * EPB;
    int i1 = i0 + EPB; if (i1 > e) i1 = e;
    for (int i = i0 + (int)threadIdx.x; i < i1; i += (int)blockDim.x) {
        int s = ei[i];
        int d = ei[e + i];
        if ((unsigned)s >= (unsigned)N_NODES || (unsigned)d >= (unsigned)N_NODES) continue;
        unsigned ent = ((unsigned)(d & 255) << 17) | (unsigned)s;
        int p = atomicAdd(&scur[(d >> BSH) * NSLOT + slot], 1);
        bins[p] = ent;
    }
}

// one block per bucket: LDS counts -> rp, dinv, then LDS-cursor scatter of col
// (bucket's ~33KB col range owned by this single block -> L2 merges lines)
__global__ __launch_bounds__(256) void k_bucket(const unsigned* __restrict__ bins,
                                                const int* __restrict__ sbase,
                                                int* __restrict__ rp, float* __restrict__ dinv,
                                                int* __restrict__ col, int n, int e) {
    int b = (int)blockIdx.x;
    int t = (int)threadIdx.x;
    int v0 = b << BSH;
    int base = sbase[b * NSLOT];
    int next = sbase[(b + 1) * NSLOT];
    __shared__ int lcnt[256], lsc[256], lcur[256];
    lcnt[t] = 0;
    __syncthreads();
    for (int i = base + t; i < next; i += 256) atomicAdd(&lcnt[bins[i] >> 17], 1);
    __syncthreads();
    int c = lcnt[t];
    lsc[t] = c;
    __syncthreads();
    for (int off = 1; off < 256; off <<= 1) {
        int x = (t >= off) ? lsc[t - off] : 0;
        __syncthreads();
        lsc[t] += x;
        __syncthreads();
    }
    int excl = lsc[t] - c;
    int v = v0 + t;
    if (v < n) {
        rp[v] = base + excl;
        dinv[v] = rsqrtf((float)(c + 1));  // +1 self-loop
    }
    if (b == 0 && t == 0) rp[n] = e;
    lcur[t] = excl;
    __syncthreads();
    for (int i = base + t; i < next; i += 256) {
        unsigned ent = bins[i];
        int p = atomicAdd(&lcur[ent >> 17], 1);
        col[base + p] = (int)(ent & 0x1FFFFu);
    }
}

// ======================= dense: h = (x @ W) * dinv[row] =======================
// LDS-tiled outer-product GEMM. Block = 64 nodes x OUT outs, 256 threads (16x16).
template <int K, int OUT, int BK>
__global__ __launch_bounds__(256) void k_gemm_tiled(const float* __restrict__ x,
                                                    const float* __restrict__ W,
                                                    const float* __restrict__ dinv,
                                                    float* __restrict__ h, int n) {
    constexpr int BM = 64;
    constexpr int TM = 4;
    constexpr int TN = OUT / 16;          // 4, 2, 1
    constexpr int PAD = 4;
    __shared__ float xs[BK][BM + PAD];
    __shared__ float ws[BK][OUT];

    int t = (int)threadIdx.x;
    int tm = t >> 4;
    int tn = t & 15;
    int m0 = blockIdx.x * BM;

    float acc[TM][TN];
#pragma unroll
    for (int i = 0; i < TM; ++i)
#pragma unroll
        for (int j = 0; j < TN; ++j) acc[i][j] = 0.0f;

    for (int kb = 0; kb < K; kb += BK) {
        if (kb) __syncthreads();
        constexpr int PER = (BM * BK) / (256 * 4);
#pragma unroll
        for (int f = 0; f < PER; ++f) {
            int flat = (f * 256 + t) * 4;
            int i = flat / BK;
            int j = flat % BK;
            int node = m0 + i;
            if (node >= n) node = n - 1;
            float4 v = *(const float4*)(x + (long long)node * K + kb + j);
            xs[j + 0][i] = v.x;
            xs[j + 1][i] = v.y;
            xs[j + 2][i] = v.z;
            xs[j + 3][i] = v.w;
        }
        constexpr int WE = BK * OUT / 4;
        for (int f = t; f < WE; f += 256) {
            int flat = f * 4;
            int k = flat / OUT;
            int o = flat % OUT;
            *(float4*)&ws[k][o] = *(const float4*)&W[(long long)(kb + k) * OUT + o];
        }
        __syncthreads();

#pragma unroll 8
        for (int k = 0; k < BK; ++k) {
            float4 av = *(const float4*)&xs[k][tm * 4];
            float a[TM] = {av.x, av.y, av.z, av.w};
            float b[TN];
            if constexpr (TN == 4) {
                float4 bv = *(const float4*)&ws[k][tn * 4];
                b[0] = bv.x; b[1] = bv.y; b[2] = bv.z; b[3] = bv.w;
            } else if constexpr (TN == 2) {
                float2 bv = *(const float2*)&ws[k][tn * 2];
                b[0] = bv.x; b[1] = bv.y;
            } else {
                b[0] = ws[k][tn];
            }
#pragma unroll
            for (int i = 0; i < TM; ++i)
#pragma unroll
                for (int j = 0; j < TN; ++j)
                    acc[i][j] = fmaf(a[i], b[j], acc[i][j]);
        }
    }

#pragma unroll
    for (int i = 0; i < TM; ++i) {
        int node = m0 + tm * 4 + i;
        if (node < n) {
            float di = dinv[node];
            float* hp = h + (long long)node * OUT + tn * TN;
#pragma unroll
            for (int j = 0; j < TN; ++j) hp[j] = acc[i][j] * di;
        }
    }
}

// per-wave gemm for the tiny final layer (K=16, OUT=4)
template <int K, int OUT, int NPW>
__global__ void k_gemm(const float* __restrict__ x, const float* __restrict__ W,
                       const float* __restrict__ dinv, float* __restrict__ h, int n) {
    constexpr int NS = 64 / OUT;
    constexpr int KC = (K < 64 * NS) ? K : 64 * NS;
    constexpr int JW = KC / NS;

    int tid = blockIdx.x * blockDim.x + threadIdx.x;
    int wid = __builtin_amdgcn_readfirstlane(tid >> 6);
    int lane = (int)threadIdx.x & 63;
    int o = lane % OUT;
    int s = lane / OUT;

    long long base = (long long)wid * NPW;
    if (base >= n) return;

    float acc[NPW];
#pragma unroll
    for (int m = 0; m < NPW; ++m) acc[m] = 0.0f;

    float w[JW];
    for (int kb = 0; kb < K; kb += KC) {
        const float* Wp = W + (long long)kb * OUT;
#pragma unroll
        for (int j = 0; j < JW; ++j) w[j] = Wp[j * 64 + lane];
#pragma unroll
        for (int m = 0; m < NPW; ++m) {
            const float* xr = x + (base + m) * K + kb;
#pragma unroll
            for (int j = 0; j < JW; ++j)
                acc[m] = fmaf(xr[j * NS + s], w[j], acc[m]);
        }
    }

#pragma unroll
    for (int m = 0; m < NPW; ++m)
#pragma unroll
        for (int off = OUT; off < 64; off <<= 1)
            acc[m] += __shfl_xor(acc[m], off, 64);

    if (s == 0) {
#pragma unroll
        for (int m = 0; m < NPW; ++m) {
            long long v = base + m;
            if (v < n) h[v * OUT + o] = acc[m] * dinv[v];
        }
    }
}

// ======================= sparse aggregate (CSR gather, no atomics) =======================
// lane = (edge-group eg, quad o4): LPR = D/4 lanes read one h row as float4;
// EG = 64/LPR edges in flight per issue. MODE: 0 = relu, 2 = log_softmax (D==4)
template <int D, int MODE>
__global__ void k_aggregate(const float* __restrict__ h, const int* __restrict__ rp,
                            const int* __restrict__ col, const float* __restrict__ dinv,
                            const float* __restrict__ b, float* __restrict__ out, int n) {
    constexpr int LPR = D / 4;
    constexpr int EG = 64 / LPR;

    int v = (int)((blockIdx.x * blockDim.x + threadIdx.x) >> 6);
    if (v >= n) return;
    int lane = (int)threadIdx.x & 63;
    int eg = lane / LPR;
    int o4 = lane % LPR;

    int beg = rp[v], end = rp[v + 1];

    float4 acc = make_float4(0.f, 0.f, 0.f, 0.f);
    for (int i = beg + eg; i < end; i += EG) {
        int s = col[i];
        float4 hv = *(const float4*)(h + (long long)s * D + o4 * 4);
        acc.x += hv.x; acc.y += hv.y; acc.z += hv.z; acc.w += hv.w;
    }

#pragma unroll
    for (int off = LPR; off < 64; off <<= 1) {
        acc.x += __shfl_xor(acc.x, off, 64);
        acc.y += __shfl_xor(acc.y, off, 64);
        acc.z += __shfl_xor(acc.z, off, 64);
        acc.w += __shfl_xor(acc.w, off, 64);
    }

    if (lane < LPR) {
        float4 self = *(const float4*)(h + (long long)v * D + o4 * 4);
        float4 bb = *(const float4*)(b + o4 * 4);
        float di = dinv[v];
        float4 val;
        val.x = di * (acc.x + self.x) + bb.x;
        val.y = di * (acc.y + self.y) + bb.y;
        val.z = di * (acc.z + self.z) + bb.z;
        val.w = di * (acc.w + self.w) + bb.w;

        if (MODE == 0) {
            val.x = fmaxf(val.x, 0.f); val.y = fmaxf(val.y, 0.f);
            val.z = fmaxf(val.z, 0.f); val.w = fmaxf(val.w, 0.f);
            *(float4*)(out + (long long)v * D + o4 * 4) = val;
        } else {
            float m = fmaxf(fmaxf(val.x, val.y), fmaxf(val.z, val.w));
            float s0 = __expf(val.x - m) + __expf(val.y - m) +
                       __expf(val.z - m) + __expf(val.w - m);
            float ls = m + __logf(s0);
            *(float4*)(out + (long long)v * 4) =
                make_float4(val.x - ls, val.y - ls, val.z - ls, val.w - ls);
        }
    }
}

// ======================= launch =======================

extern "C" void kernel_launch(void* const* d_in, const int* in_sizes, int n_in,
                              void* d_out, int out_size, void* d_ws, size_t ws_size,
                              hipStream_t stream) {
    const float* x = (const float*)d_in[0];
    const int* ei = (const int*)d_in[1];  // int32 [2, E]
    const float* W1 = (const float*)d_in[2];
    const float* b1 = (const float*)d_in[3];
    const float* W2 = (const float*)d_in[4];
    const float* b2 = (const float*)d_in[5];
    const float* W3 = (const float*)d_in[6];
    const float* b3 = (const float*)d_in[7];
    const float* W4 = (const float*)d_in[8];
    const float* b4 = (const float*)d_in[9];
    float* out = (float*)d_out;

    const int n = N_NODES;
    const int e = N_EDGES;
    const int B = 256;
    constexpr int M = NB * NSLOT;  // 3128

    char* ws = (char*)d_ws;
    size_t off = 0;
    auto alloc = [&](size_t bytes) {
        void* p = ws + off;
        off += (bytes + 255) & ~size_t(255);
        return p;
    };
    float* dinv = (float*)alloc((size_t)n * 4);
    int* rp = (int*)alloc((size_t)(n + 1) * 4);
    int* cnt2 = (int*)alloc((size_t)M * 4);
    int* sbase = (int*)alloc((size_t)(M + 1) * 4);
    int* scur = (int*)alloc((size_t)M * 4);
    unsigned* bins = (unsigned*)alloc((size_t)e * 4);
    int* col = (int*)alloc((size_t)e * 4);
    float* H = (float*)alloc((size_t)n * 64 * 4);
    float* A = (float*)alloc((size_t)n * 64 * 4);

    // ---- CSR build (two-phase binned) ----
    k_zero_int<<<(M + B - 1) / B, B, 0, stream>>>(cnt2, M);
    k_hist2<<<(e / 4 + B - 1) / B, B, 0, stream>>>(ei, cnt2, e);
    k_scan3k<<<1, 1024, 0, stream>>>(cnt2, sbase, scur, e);
    k_bin<<<G_BIN, B, 0, stream>>>(ei, scur, bins, e);
    k_bucket<<<NB, B, 0, stream>>>(bins, sbase, rp, dinv, col, n, e);

    const int gblk = (n + 63) / 64;   // tiled gemm blocks (BM=64)
    const int ablk = (n + 3) / 4;     // aggregate blocks (4 waves / block)

    // ---- layer 1: 256 -> 64, relu ----
    {
        k_gemm_tiled<256, 64, 64><<<gblk, B, 0, stream>>>(x, W1, dinv, H, n);
        k_aggregate<64, 0><<<ablk, B, 0, stream>>>(H, rp, col, dinv, b1, A, n);
    }
    // ---- layer 2: 64 -> 32, relu ----
    {
        k_gemm_tiled<64, 32, 64><<<gblk, B, 0, stream>>>(A, W2, dinv, H, n);
        k_aggregate<32, 0><<<ablk, B, 0, stream>>>(H, rp, col, dinv, b2, A, n);
    }
    // ---- layer 3: 32 -> 16, relu ----
    {
        k_gemm_tiled<32, 16, 32><<<gblk, B, 0, stream>>>(A, W3, dinv, H, n);
        k_aggregate<16, 0><<<ablk, B, 0, stream>>>(H, rp, col, dinv, b3, A, n);
    }
    // ---- layer 4: 16 -> 4, log_softmax ----
    {
        constexpr int NPW = 16;
        const int g4 = ((n + NPW - 1) / NPW + 3) / 4;
        k_gemm<16, 4, NPW><<<g4, B, 0, stream>>>(A, W4, dinv, H, n);
        k_aggregate<4, 2><<<ablk, B, 0, stream>>>(H, rp, col, dinv, b4, out, n);
    }
}

// Round 8
// 672.220 us; speedup vs baseline: 1.4339x; 1.4339x over previous
//
#include <hip/hip_runtime.h>

#define N_NODES 100000
#define N_EDGES 3200000

// CSR binning geometry
#define BSH 8                        // 256 nodes per bucket
#define NB 391                       // ceil(100000/256)
#define NSLOT 8                      // one slot per XCD (slot = XCC_ID)
#define CAPS 3072                    // entries per (bucket,slot) region (mean ~1023)
#define CAPB 9216                    // col entries per bucket (mean ~8184, +11 sigma)
#define OVF_CAP (1 << 20)            // overflow entries (normally 0)

// hwreg(HW_REG_XCC_ID=20, offset=0, size=32) -> imm = 20 | (31<<11)
#define XCC_GETREG_IMM 63508

// ======================= CSR build (single-pass, XCD-slotted) =======================

__global__ void k_zero_int(int* __restrict__ p, int n) {
    int i = blockIdx.x * blockDim.x + threadIdx.x;
    if (i < n) p[i] = 0;
}

// append packed (dst_low<<17 | src) into (bucket, slot=XCC_ID) regions.
// Region writes come from exactly one XCD -> its L2 owns the frontier lines.
__global__ void k_bin(const int* __restrict__ ei, int* __restrict__ scur,
                      int* __restrict__ ovfc, unsigned* __restrict__ bins,
                      int2* __restrict__ ovf, int e) {
    int tid = blockIdx.x * blockDim.x + threadIdx.x;
    int slot = (int)(__builtin_amdgcn_s_getreg(XCC_GETREG_IMM)) & (NSLOT - 1);
    int i4 = tid * 4;
    if (i4 + 3 >= e && i4 >= e) return;
    int4 s4 = *(const int4*)(ei + i4);
    int4 d4 = *(const int4*)(ei + e + i4);
    int ss[4] = {s4.x, s4.y, s4.z, s4.w};
    int dd[4] = {d4.x, d4.y, d4.z, d4.w};
#pragma unroll
    for (int j = 0; j < 4; ++j) {
        int s = ss[j], d = dd[j];
        if ((unsigned)s >= (unsigned)N_NODES || (unsigned)d >= (unsigned)N_NODES) continue;
        int reg = ((d >> BSH) << 3) + slot;
        int p = atomicAdd(&scur[reg], 1);
        if (p < CAPS) {
            bins[(long long)reg * CAPS + p] = ((unsigned)(d & 255) << 17) | (unsigned)s;
        } else {
            int q = atomicAdd(ovfc, 1);
            if (q < OVF_CAP) ovf[q] = make_int2(s, d);
        }
    }
}

// one block per bucket: LDS hist -> rp_beg/rp_end/dinv, then LDS-cursor scatter
// of col within the block-exclusive [b*CAPB, ...) range (single-XCD writeback).
__global__ __launch_bounds__(256) void k_bucket(const unsigned* __restrict__ bins,
                                                const int* __restrict__ scur,
                                                const int* __restrict__ ovfc,
                                                const int2* __restrict__ ovf,
                                                int* __restrict__ rpb, int* __restrict__ rpe,
                                                float* __restrict__ dinv,
                                                int* __restrict__ col, int n) {
    int b = (int)blockIdx.x;
    int t = (int)threadIdx.x;
    __shared__ int lcnt[256], lsc[256], lcur[256];
    __shared__ int rcnt[NSLOT];
    lcnt[t] = 0;
    if (t < NSLOT) {
        int c = scur[b * NSLOT + t];
        rcnt[t] = c < CAPS ? c : CAPS;
    }
    __syncthreads();
    int novf = *ovfc;
    if (novf > OVF_CAP) novf = OVF_CAP;

    // ---- pass 1: per-node counts ----
#pragma unroll
    for (int s = 0; s < NSLOT; ++s) {
        const unsigned* reg = bins + (long long)(b * NSLOT + s) * CAPS;
        int c = rcnt[s];
        for (int i = t; i < c; i += 256) atomicAdd(&lcnt[reg[i] >> 17], 1);
    }
    for (int i = t; i < novf; i += 256) {
        int2 pr = ovf[i];
        if ((pr.y >> BSH) == b) atomicAdd(&lcnt[pr.y & 255], 1);
    }
    __syncthreads();

    // ---- scan 256 ----
    int c = lcnt[t];
    lsc[t] = c;
    __syncthreads();
    for (int off = 1; off < 256; off <<= 1) {
        int x = (t >= off) ? lsc[t - off] : 0;
        __syncthreads();
        lsc[t] += x;
        __syncthreads();
    }
    int excl = lsc[t] - c;
    int base = b * CAPB;
    int v = (b << BSH) + t;
    if (v < n) {
        rpb[v] = base + excl;
        rpe[v] = base + excl + c;
        dinv[v] = rsqrtf((float)(c + 1));  // +1 self-loop
    }
    lcur[t] = excl;
    __syncthreads();

    // ---- pass 2: scatter col (region re-read hits L2) ----
#pragma unroll
    for (int s = 0; s < NSLOT; ++s) {
        const unsigned* reg = bins + (long long)(b * NSLOT + s) * CAPS;
        int cc = rcnt[s];
        for (int i = t; i < cc; i += 256) {
            unsigned ent = reg[i];
            int p = atomicAdd(&lcur[ent >> 17], 1);
            col[base + p] = (int)(ent & 0x1FFFFu);
        }
    }
    for (int i = t; i < novf; i += 256) {
        int2 pr = ovf[i];
        if ((pr.y >> BSH) == b) {
            int p = atomicAdd(&lcur[pr.y & 255], 1);
            col[base + p] = pr.x;
        }
    }
}

// ======================= dense: h = (x @ W) * dinv[row] =======================
// LDS-tiled outer-product GEMM. Block = 64 nodes x OUT outs, 256 threads (16x16).
template <int K, int OUT, int BK>
__global__ __launch_bounds__(256) void k_gemm_tiled(const float* __restrict__ x,
                                                    const float* __restrict__ W,
                                                    const float* __restrict__ dinv,
                                                    float* __restrict__ h, int n) {
    constexpr int BM = 64;
    constexpr int TM = 4;
    constexpr int TN = OUT / 16;          // 4, 2, 1
    constexpr int PAD = 4;
    __shared__ float xs[BK][BM + PAD];
    __shared__ float ws[BK][OUT];

    int t = (int)threadIdx.x;
    int tm = t >> 4;
    int tn = t & 15;
    int m0 = blockIdx.x * BM;

    float acc[TM][TN];
#pragma unroll
    for (int i = 0; i < TM; ++i)
#pragma unroll
        for (int j = 0; j < TN; ++j) acc[i][j] = 0.0f;

    for (int kb = 0; kb < K; kb += BK) {
        if (kb) __syncthreads();
        constexpr int PER = (BM * BK) / (256 * 4);
#pragma unroll
        for (int f = 0; f < PER; ++f) {
            int flat = (f * 256 + t) * 4;
            int i = flat / BK;
            int j = flat % BK;
            int node = m0 + i;
            if (node >= n) node = n - 1;
            float4 v = *(const float4*)(x + (long long)node * K + kb + j);
            xs[j + 0][i] = v.x;
            xs[j + 1][i] = v.y;
            xs[j + 2][i] = v.z;
            xs[j + 3][i] = v.w;
        }
        constexpr int WE = BK * OUT / 4;
        for (int f = t; f < WE; f += 256) {
            int flat = f * 4;
            int k = flat / OUT;
            int o = flat % OUT;
            *(float4*)&ws[k][o] = *(const float4*)&W[(long long)(kb + k) * OUT + o];
        }
        __syncthreads();

#pragma unroll 8
        for (int k = 0; k < BK; ++k) {
            float4 av = *(const float4*)&xs[k][tm * 4];
            float a[TM] = {av.x, av.y, av.z, av.w};
            float b[TN];
            if constexpr (TN == 4) {
                float4 bv = *(const float4*)&ws[k][tn * 4];
                b[0] = bv.x; b[1] = bv.y; b[2] = bv.z; b[3] = bv.w;
            } else if constexpr (TN == 2) {
                float2 bv = *(const float2*)&ws[k][tn * 2];
                b[0] = bv.x; b[1] = bv.y;
            } else {
                b[0] = ws[k][tn];
            }
#pragma unroll
            for (int i = 0; i < TM; ++i)
#pragma unroll
                for (int j = 0; j < TN; ++j)
                    acc[i][j] = fmaf(a[i], b[j], acc[i][j]);
        }
    }

#pragma unroll
    for (int i = 0; i < TM; ++i) {
        int node = m0 + tm * 4 + i;
        if (node < n) {
            float di = dinv[node];
            float* hp = h + (long long)node * OUT + tn * TN;
#pragma unroll
            for (int j = 0; j < TN; ++j) hp[j] = acc[i][j] * di;
        }
    }
}

// per-wave gemm for the tiny final layer (K=16, OUT=4)
template <int K, int OUT, int NPW>
__global__ void k_gemm(const float* __restrict__ x, const float* __restrict__ W,
                       const float* __restrict__ dinv, float* __restrict__ h, int n) {
    constexpr int NS = 64 / OUT;
    constexpr int KC = (K < 64 * NS) ? K : 64 * NS;
    constexpr int JW = KC / NS;

    int tid = blockIdx.x * blockDim.x + threadIdx.x;
    int wid = __builtin_amdgcn_readfirstlane(tid >> 6);
    int lane = (int)threadIdx.x & 63;
    int o = lane % OUT;
    int s = lane / OUT;

    long long base = (long long)wid * NPW;
    if (base >= n) return;

    float acc[NPW];
#pragma unroll
    for (int m = 0; m < NPW; ++m) acc[m] = 0.0f;

    float w[JW];
    for (int kb = 0; kb < K; kb += KC) {
        const float* Wp = W + (long long)kb * OUT;
#pragma unroll
        for (int j = 0; j < JW; ++j) w[j] = Wp[j * 64 + lane];
#pragma unroll
        for (int m = 0; m < NPW; ++m) {
            const float* xr = x + (base + m) * K + kb;
#pragma unroll
            for (int j = 0; j < JW; ++j)
                acc[m] = fmaf(xr[j * NS + s], w[j], acc[m]);
        }
    }

#pragma unroll
    for (int m = 0; m < NPW; ++m)
#pragma unroll
        for (int off = OUT; off < 64; off <<= 1)
            acc[m] += __shfl_xor(acc[m], off, 64);

    if (s == 0) {
#pragma unroll
        for (int m = 0; m < NPW; ++m) {
            long long v = base + m;
            if (v < n) h[v * OUT + o] = acc[m] * dinv[v];
        }
    }
}

// ======================= sparse aggregate (CSR gather, no atomics) =======================
// lane = (edge-group eg, quad o4): LPR = D/4 lanes read one h row as float4;
// EG = 64/LPR edges in flight per issue. MODE: 0 = relu, 2 = log_softmax (D==4)
template <int D, int MODE>
__global__ void k_aggregate(const float* __restrict__ h, const int* __restrict__ rpb,
                            const int* __restrict__ rpe, const int* __restrict__ col,
                            const float* __restrict__ dinv, const float* __restrict__ b,
                            float* __restrict__ out, int n) {
    constexpr int LPR = D / 4;
    constexpr int EG = 64 / LPR;

    int v = (int)((blockIdx.x * blockDim.x + threadIdx.x) >> 6);
    if (v >= n) return;
    int lane = (int)threadIdx.x & 63;
    int eg = lane / LPR;
    int o4 = lane % LPR;

    int beg = rpb[v], end = rpe[v];

    float4 acc = make_float4(0.f, 0.f, 0.f, 0.f);
    for (int i = beg + eg; i < end; i += EG) {
        int s = col[i];
        float4 hv = *(const float4*)(h + (long long)s * D + o4 * 4);
        acc.x += hv.x; acc.y += hv.y; acc.z += hv.z; acc.w += hv.w;
    }

#pragma unroll
    for (int off = LPR; off < 64; off <<= 1) {
        acc.x += __shfl_xor(acc.x, off, 64);
        acc.y += __shfl_xor(acc.y, off, 64);
        acc.z += __shfl_xor(acc.z, off, 64);
        acc.w += __shfl_xor(acc.w, off, 64);
    }

    if (lane < LPR) {
        float4 self = *(const float4*)(h + (long long)v * D + o4 * 4);
        float4 bb = *(const float4*)(b + o4 * 4);
        float di = dinv[v];
        float4 val;
        val.x = di * (acc.x + self.x) + bb.x;
        val.y = di * (acc.y + self.y) + bb.y;
        val.z = di * (acc.z + self.z) + bb.z;
        val.w = di * (acc.w + self.w) + bb.w;

        if (MODE == 0) {
            val.x = fmaxf(val.x, 0.f); val.y = fmaxf(val.y, 0.f);
            val.z = fmaxf(val.z, 0.f); val.w = fmaxf(val.w, 0.f);
            *(float4*)(out + (long long)v * D + o4 * 4) = val;
        } else {
            float m = fmaxf(fmaxf(val.x, val.y), fmaxf(val.z, val.w));
            float s0 = __expf(val.x - m) + __expf(val.y - m) +
                       __expf(val.z - m) + __expf(val.w - m);
            float ls = m + __logf(s0);
            *(float4*)(out + (long long)v * 4) =
                make_float4(val.x - ls, val.y - ls, val.z - ls, val.w - ls);
        }
    }
}

// ======================= launch =======================

extern "C" void kernel_launch(void* const* d_in, const int* in_sizes, int n_in,
                              void* d_out, int out_size, void* d_ws, size_t ws_size,
                              hipStream_t stream) {
    const float* x = (const float*)d_in[0];
    const int* ei = (const int*)d_in[1];  // int32 [2, E]
    const float* W1 = (const float*)d_in[2];
    const float* b1 = (const float*)d_in[3];
    const float* W2 = (const float*)d_in[4];
    const float* b2 = (const float*)d_in[5];
    const float* W3 = (const float*)d_in[6];
    const float* b3 = (const float*)d_in[7];
    const float* W4 = (const float*)d_in[8];
    const float* b4 = (const float*)d_in[9];
    float* out = (float*)d_out;

    const int n = N_NODES;
    const int e = N_EDGES;
    const int B = 256;
    constexpr int M = NB * NSLOT;  // 3128

    char* ws = (char*)d_ws;
    size_t off = 0;
    auto alloc = [&](size_t bytes) {
        void* p = ws + off;
        off += (bytes + 255) & ~size_t(255);
        return p;
    };
    float* dinv = (float*)alloc((size_t)n * 4);
    int* rpb = (int*)alloc((size_t)n * 4);
    int* rpe = (int*)alloc((size_t)n * 4);
    int* scur = (int*)alloc((size_t)(M + 1) * 4);      // + ovf counter
    unsigned* bins = (unsigned*)alloc((size_t)M * CAPS * 4);   // 38.4 MB
    int2* ovf = (int2*)alloc((size_t)OVF_CAP * 8);             // 8 MB
    int* col = (int*)alloc((size_t)NB * CAPB * 4);             // 14.4 MB
    float* H = (float*)alloc((size_t)n * 64 * 4);
    float* A = (float*)alloc((size_t)n * 64 * 4);
    int* ovfc = scur + M;

    // ---- CSR build (single-pass, XCD-slotted) ----
    k_zero_int<<<(M + 1 + B - 1) / B, B, 0, stream>>>(scur, M + 1);
    k_bin<<<e / 4 / B, B, 0, stream>>>(ei, scur, ovfc, bins, ovf, e);
    k_bucket<<<NB, B, 0, stream>>>(bins, scur, ovfc, ovf, rpb, rpe, dinv, col, n);

    const int gblk = (n + 63) / 64;   // tiled gemm blocks (BM=64)
    const int ablk = (n + 3) / 4;     // aggregate blocks (4 waves / block)

    // ---- layer 1: 256 -> 64, relu ----
    {
        k_gemm_tiled<256, 64, 64><<<gblk, B, 0, stream>>>(x, W1, dinv, H, n);
        k_aggregate<64, 0><<<ablk, B, 0, stream>>>(H, rpb, rpe, col, dinv, b1, A, n);
    }
    // ---- layer 2: 64 -> 32, relu ----
    {
        k_gemm_tiled<64, 32, 64><<<gblk, B, 0, stream>>>(A, W2, dinv, H, n);
        k_aggregate<32, 0><<<ablk, B, 0, stream>>>(H, rpb, rpe, col, dinv, b2, A, n);
    }
    // ---- layer 3: 32 -> 16, relu ----
    {
        k_gemm_tiled<32, 16, 32><<<gblk, B, 0, stream>>>(A, W3, dinv, H, n);
        k_aggregate<16, 0><<<ablk, B, 0, stream>>>(H, rpb, rpe, col, dinv, b3, A, n);
    }
    // ---- layer 4: 16 -> 4, log_softmax ----
    {
        constexpr int NPW = 16;
        const int g4 = ((n + NPW - 1) / NPW + 3) / 4;
        k_gemm<16, 4, NPW><<<g4, B, 0, stream>>>(A, W4, dinv, H, n);
        k_aggregate<4, 2><<<ablk, B, 0, stream>>>(H, rpb, rpe, col, dinv, b4, out, n);
    }
}

// Round 9
// 436.182 us; speedup vs baseline: 2.2099x; 1.5411x over previous
//
#include <hip/hip_runtime.h>

#define N_NODES 100000
#define N_EDGES 3200000

// CSR sort geometry
#define BSH 8                        // 256 nodes per bucket
#define NB 391                       // ceil(100000/256)
#define G_SRT 256                    // blocks in hist/scatter pass
#define EPB ((N_EDGES + G_SRT - 1) / G_SRT)   // 12500 edges per block
#define HP 392                       // hist row pitch

// ======================= CSR build (one-pass multisplit, no global atomics) =======================

// per-block histogram over 391 dst-buckets
__global__ __launch_bounds__(256) void k_hist_blk(const int* __restrict__ ei,
                                                  int* __restrict__ hist, int e) {
    __shared__ int lh[NB];
    int b = (int)blockIdx.x, t = (int)threadIdx.x;
    for (int k = t; k < NB; k += 256) lh[k] = 0;
    __syncthreads();
    int i0 = b * EPB, i1 = i0 + EPB; if (i1 > e) i1 = e;
    for (int i = i0 + t; i < i1; i += 256) {
        int d = ei[e + i];
        if ((unsigned)d < (unsigned)N_NODES) atomicAdd(&lh[d >> BSH], 1);
    }
    __syncthreads();
    for (int k = t; k < NB; k += 256) hist[b * HP + k] = lh[k];
}

// per-bucket exclusive scan across blocks -> offs[bucket][block], totals
__global__ __launch_bounds__(256) void k_scan_col(const int* __restrict__ hist,
                                                  int* __restrict__ offs, int* __restrict__ tot) {
    __shared__ int sm[256];
    int k = (int)blockIdx.x, t = (int)threadIdx.x;
    int v = hist[t * HP + k];
    sm[t] = v;
    __syncthreads();
    for (int off = 1; off < 256; off <<= 1) {
        int x = (t >= off) ? sm[t - off] : 0;
        __syncthreads();
        sm[t] += x;
        __syncthreads();
    }
    offs[k * G_SRT + t] = sm[t] - v;
    if (t == 255) tot[k] = sm[255];
}

// scan bucket totals -> bBase[0..NB]
__global__ void k_scan_tot(const int* __restrict__ tot, int* __restrict__ bBase) {
    __shared__ int sm[512];
    int t = (int)threadIdx.x;
    int v = (t < NB) ? tot[t] : 0;
    sm[t] = v;
    __syncthreads();
    for (int off = 1; off < 512; off <<= 1) {
        int x = (t >= off) ? sm[t - off] : 0;
        __syncthreads();
        sm[t] += x;
        __syncthreads();
    }
    if (t < NB) bBase[t] = sm[t] - v;
    if (t == NB - 1) bBase[NB] = sm[t];
}

// block-local multisplit: LDS-rank + LDS-staged tile, then contiguous segment copies.
// bins ends up globally bucket-contiguous; block's writes land in pre-reserved ranges.
__global__ __launch_bounds__(256) void k_scatter_srt(const int* __restrict__ ei,
                                                     const int* __restrict__ offs,
                                                     const int* __restrict__ bBase,
                                                     unsigned* __restrict__ bins, int e) {
    __shared__ unsigned sbuf[EPB];                 // 50 KB staging
    __shared__ int lh[NB], lcur[NB], gdst[NB];
    __shared__ int sA[NB], sBf[NB];
    int b = (int)blockIdx.x, t = (int)threadIdx.x;
    int i0 = b * EPB, i1 = i0 + EPB; if (i1 > e) i1 = e;

    for (int k = t; k < NB; k += 256) lh[k] = 0;
    __syncthreads();
    for (int i = i0 + t; i < i1; i += 256) {
        int d = ei[e + i];
        if ((unsigned)d < (unsigned)N_NODES) atomicAdd(&lh[d >> BSH], 1);
    }
    __syncthreads();

    // inclusive scan over NB buckets (double-buffered Hillis-Steele)
    int* cur = sA; int* nxt = sBf;
    for (int k = t; k < NB; k += 256) cur[k] = lh[k];
    __syncthreads();
    for (int off = 1; off < NB; off <<= 1) {
        for (int k = t; k < NB; k += 256) nxt[k] = cur[k] + (k >= off ? cur[k - off] : 0);
        __syncthreads();
        int* tmp = cur; cur = nxt; nxt = tmp;
    }
    for (int k = t; k < NB; k += 256) {
        lcur[k] = cur[k] - lh[k];                       // local exclusive base
        gdst[k] = bBase[k] + offs[k * G_SRT + b];       // global dest base
    }
    __syncthreads();

    // rank + stage into LDS (sorted by bucket within the tile)
    for (int i = i0 + t; i < i1; i += 256) {
        int s = ei[i];
        int d = ei[e + i];
        if ((unsigned)s >= (unsigned)N_NODES || (unsigned)d >= (unsigned)N_NODES) continue;
        int k = d >> BSH;
        int p = atomicAdd(&lcur[k], 1);
        sbuf[p] = ((unsigned)(d & 255) << 17) | (unsigned)s;
    }
    __syncthreads();

    // contiguous copies: LDS segment -> pre-reserved global segment
    int wv = t >> 6, ln = t & 63;
    for (int k = wv; k < NB; k += 4) {
        int cnt = lh[k];
        int src0 = lcur[k] - cnt;
        int dst0 = gdst[k];
        for (int j = ln; j < cnt; j += 64) bins[dst0 + j] = sbuf[src0 + j];
    }
}

// one block per bucket: LDS hist -> rp/dinv, then LDS-cursor scatter of col
__global__ __launch_bounds__(256) void k_bucket(const unsigned* __restrict__ bins,
                                                const int* __restrict__ bBase,
                                                int* __restrict__ rpb, int* __restrict__ rpe,
                                                float* __restrict__ dinv,
                                                int* __restrict__ col, int n) {
    int b = (int)blockIdx.x;
    int t = (int)threadIdx.x;
    int base = bBase[b], next = bBase[b + 1];
    __shared__ int lcnt[256], lsc[256], lcur[256];
    lcnt[t] = 0;
    __syncthreads();
    for (int i = base + t; i < next; i += 256) atomicAdd(&lcnt[bins[i] >> 17], 1);
    __syncthreads();
    int c = lcnt[t];
    lsc[t] = c;
    __syncthreads();
    for (int off = 1; off < 256; off <<= 1) {
        int x = (t >= off) ? lsc[t - off] : 0;
        __syncthreads();
        lsc[t] += x;
        __syncthreads();
    }
    int excl = lsc[t] - c;
    int v = (b << BSH) + t;
    if (v < n) {
        rpb[v] = base + excl;
        rpe[v] = base + excl + c;
        dinv[v] = rsqrtf((float)(c + 1));  // +1 self-loop
    }
    lcur[t] = excl;
    __syncthreads();
    for (int i = base + t; i < next; i += 256) {
        unsigned ent = bins[i];
        int p = atomicAdd(&lcur[ent >> 17], 1);
        col[base + p] = (int)(ent & 0x1FFFFu);
    }
}

// ======================= dense: h = (x @ W) * dinv[row] =======================
// LDS-tiled outer-product GEMM. Block = 64 nodes x OUT outs, 256 threads (16x16).
template <int K, int OUT, int BK>
__global__ __launch_bounds__(256) void k_gemm_tiled(const float* __restrict__ x,
                                                    const float* __restrict__ W,
                                                    const float* __restrict__ dinv,
                                                    float* __restrict__ h, int n) {
    constexpr int BM = 64;
    constexpr int TM = 4;
    constexpr int TN = OUT / 16;          // 4, 2, 1
    constexpr int PAD = 4;
    __shared__ float xs[BK][BM + PAD];
    __shared__ float ws[BK][OUT];

    int t = (int)threadIdx.x;
    int tm = t >> 4;
    int tn = t & 15;
    int m0 = blockIdx.x * BM;

    float acc[TM][TN];
#pragma unroll
    for (int i = 0; i < TM; ++i)
#pragma unroll
        for (int j = 0; j < TN; ++j) acc[i][j] = 0.0f;

    for (int kb = 0; kb < K; kb += BK) {
        if (kb) __syncthreads();
        constexpr int PER = (BM * BK) / (256 * 4);
#pragma unroll
        for (int f = 0; f < PER; ++f) {
            int flat = (f * 256 + t) * 4;
            int i = flat / BK;
            int j = flat % BK;
            int node = m0 + i;
            if (node >= n) node = n - 1;
            float4 v = *(const float4*)(x + (long long)node * K + kb + j);
            xs[j + 0][i] = v.x;
            xs[j + 1][i] = v.y;
            xs[j + 2][i] = v.z;
            xs[j + 3][i] = v.w;
        }
        constexpr int WE = BK * OUT / 4;
        for (int f = t; f < WE; f += 256) {
            int flat = f * 4;
            int k = flat / OUT;
            int o = flat % OUT;
            *(float4*)&ws[k][o] = *(const float4*)&W[(long long)(kb + k) * OUT + o];
        }
        __syncthreads();

#pragma unroll 8
        for (int k = 0; k < BK; ++k) {
            float4 av = *(const float4*)&xs[k][tm * 4];
            float a[TM] = {av.x, av.y, av.z, av.w};
            float b[TN];
            if constexpr (TN == 4) {
                float4 bv = *(const float4*)&ws[k][tn * 4];
                b[0] = bv.x; b[1] = bv.y; b[2] = bv.z; b[3] = bv.w;
            } else if constexpr (TN == 2) {
                float2 bv = *(const float2*)&ws[k][tn * 2];
                b[0] = bv.x; b[1] = bv.y;
            } else {
                b[0] = ws[k][tn];
            }
#pragma unroll
            for (int i = 0; i < TM; ++i)
#pragma unroll
                for (int j = 0; j < TN; ++j)
                    acc[i][j] = fmaf(a[i], b[j], acc[i][j]);
        }
    }

#pragma unroll
    for (int i = 0; i < TM; ++i) {
        int node = m0 + tm * 4 + i;
        if (node < n) {
            float di = dinv[node];
            float* hp = h + (long long)node * OUT + tn * TN;
#pragma unroll
            for (int j = 0; j < TN; ++j) hp[j] = acc[i][j] * di;
        }
    }
}

// per-wave gemm for the tiny final layer (K=16, OUT=4)
template <int K, int OUT, int NPW>
__global__ void k_gemm(const float* __restrict__ x, const float* __restrict__ W,
                       const float* __restrict__ dinv, float* __restrict__ h, int n) {
    constexpr int NS = 64 / OUT;
    constexpr int KC = (K < 64 * NS) ? K : 64 * NS;
    constexpr int JW = KC / NS;

    int tid = blockIdx.x * blockDim.x + threadIdx.x;
    int wid = __builtin_amdgcn_readfirstlane(tid >> 6);
    int lane = (int)threadIdx.x & 63;
    int o = lane % OUT;
    int s = lane / OUT;

    long long base = (long long)wid * NPW;
    if (base >= n) return;

    float acc[NPW];
#pragma unroll
    for (int m = 0; m < NPW; ++m) acc[m] = 0.0f;

    float w[JW];
    for (int kb = 0; kb < K; kb += KC) {
        const float* Wp = W + (long long)kb * OUT;
#pragma unroll
        for (int j = 0; j < JW; ++j) w[j] = Wp[j * 64 + lane];
#pragma unroll
        for (int m = 0; m < NPW; ++m) {
            const float* xr = x + (base + m) * K + kb;
#pragma unroll
            for (int j = 0; j < JW; ++j)
                acc[m] = fmaf(xr[j * NS + s], w[j], acc[m]);
        }
    }

#pragma unroll
    for (int m = 0; m < NPW; ++m)
#pragma unroll
        for (int off = OUT; off < 64; off <<= 1)
            acc[m] += __shfl_xor(acc[m], off, 64);

    if (s == 0) {
#pragma unroll
        for (int m = 0; m < NPW; ++m) {
            long long v = base + m;
            if (v < n) h[v * OUT + o] = acc[m] * dinv[v];
        }
    }
}

// ======================= sparse aggregate (CSR gather, no atomics) =======================
// lane = (edge-group eg, quad o4): LPR = D/4 lanes read one h row as float4;
// EG = 64/LPR edges in flight per issue. MODE: 0 = relu, 2 = log_softmax (D==4)
template <int D, int MODE>
__global__ void k_aggregate(const float* __restrict__ h, const int* __restrict__ rpb,
                            const int* __restrict__ rpe, const int* __restrict__ col,
                            const float* __restrict__ dinv, const float* __restrict__ b,
                            float* __restrict__ out, int n) {
    constexpr int LPR = D / 4;
    constexpr int EG = 64 / LPR;

    int v = (int)((blockIdx.x * blockDim.x + threadIdx.x) >> 6);
    if (v >= n) return;
    int lane = (int)threadIdx.x & 63;
    int eg = lane / LPR;
    int o4 = lane % LPR;

    int beg = rpb[v], end = rpe[v];

    float4 acc = make_float4(0.f, 0.f, 0.f, 0.f);
    for (int i = beg + eg; i < end; i += EG) {
        int s = col[i];
        float4 hv = *(const float4*)(h + (long long)s * D + o4 * 4);
        acc.x += hv.x; acc.y += hv.y; acc.z += hv.z; acc.w += hv.w;
    }

#pragma unroll
    for (int off = LPR; off < 64; off <<= 1) {
        acc.x += __shfl_xor(acc.x, off, 64);
        acc.y += __shfl_xor(acc.y, off, 64);
        acc.z += __shfl_xor(acc.z, off, 64);
        acc.w += __shfl_xor(acc.w, off, 64);
    }

    if (lane < LPR) {
        float4 self = *(const float4*)(h + (long long)v * D + o4 * 4);
        float4 bb = *(const float4*)(b + o4 * 4);
        float di = dinv[v];
        float4 val;
        val.x = di * (acc.x + self.x) + bb.x;
        val.y = di * (acc.y + self.y) + bb.y;
        val.z = di * (acc.z + self.z) + bb.z;
        val.w = di * (acc.w + self.w) + bb.w;

        if (MODE == 0) {
            val.x = fmaxf(val.x, 0.f); val.y = fmaxf(val.y, 0.f);
            val.z = fmaxf(val.z, 0.f); val.w = fmaxf(val.w, 0.f);
            *(float4*)(out + (long long)v * D + o4 * 4) = val;
        } else {
            float m = fmaxf(fmaxf(val.x, val.y), fmaxf(val.z, val.w));
            float s0 = __expf(val.x - m) + __expf(val.y - m) +
                       __expf(val.z - m) + __expf(val.w - m);
            float ls = m + __logf(s0);
            *(float4*)(out + (long long)v * 4) =
                make_float4(val.x - ls, val.y - ls, val.z - ls, val.w - ls);
        }
    }
}

// ======================= launch =======================

extern "C" void kernel_launch(void* const* d_in, const int* in_sizes, int n_in,
                              void* d_out, int out_size, void* d_ws, size_t ws_size,
                              hipStream_t stream) {
    const float* x = (const float*)d_in[0];
    const int* ei = (const int*)d_in[1];  // int32 [2, E]
    const float* W1 = (const float*)d_in[2];
    const float* b1 = (const float*)d_in[3];
    const float* W2 = (const float*)d_in[4];
    const float* b2 = (const float*)d_in[5];
    const float* W3 = (const float*)d_in[6];
    const float* b3 = (const float*)d_in[7];
    const float* W4 = (const float*)d_in[8];
    const float* b4 = (const float*)d_in[9];
    float* out = (float*)d_out;

    const int n = N_NODES;
    const int e = N_EDGES;
    const int B = 256;

    char* ws = (char*)d_ws;
    size_t off = 0;
    auto alloc = [&](size_t bytes) {
        void* p = ws + off;
        off += (bytes + 255) & ~size_t(255);
        return p;
    };
    float* dinv = (float*)alloc((size_t)n * 4);
    int* rpb = (int*)alloc((size_t)n * 4);
    int* rpe = (int*)alloc((size_t)n * 4);
    int* hist = (int*)alloc((size_t)G_SRT * HP * 4);     // 400 KB
    int* offs = (int*)alloc((size_t)NB * G_SRT * 4);     // 400 KB
    int* tot = (int*)alloc((size_t)NB * 4);
    int* bBase = (int*)alloc((size_t)(NB + 1) * 4);
    unsigned* bins = (unsigned*)alloc((size_t)e * 4);    // 12.8 MB
    int* col = (int*)alloc((size_t)e * 4);               // 12.8 MB
    float* H = (float*)alloc((size_t)n * 64 * 4);
    float* A = (float*)alloc((size_t)n * 64 * 4);

    // ---- CSR build (multisplit, no global atomics) ----
    k_hist_blk<<<G_SRT, B, 0, stream>>>(ei, hist, e);
    k_scan_col<<<NB, B, 0, stream>>>(hist, offs, tot);
    k_scan_tot<<<1, 512, 0, stream>>>(tot, bBase);
    k_scatter_srt<<<G_SRT, B, 0, stream>>>(ei, offs, bBase, bins, e);
    k_bucket<<<NB, B, 0, stream>>>(bins, bBase, rpb, rpe, dinv, col, n);

    const int gblk = (n + 63) / 64;   // tiled gemm blocks (BM=64)
    const int ablk = (n + 3) / 4;     // aggregate blocks (4 waves / block)

    // ---- layer 1: 256 -> 64, relu ----
    {
        k_gemm_tiled<256, 64, 64><<<gblk, B, 0, stream>>>(x, W1, dinv, H, n);
        k_aggregate<64, 0><<<ablk, B, 0, stream>>>(H, rpb, rpe, col, dinv, b1, A, n);
    }
    // ---- layer 2: 64 -> 32, relu ----
    {
        k_gemm_tiled<64, 32, 64><<<gblk, B, 0, stream>>>(A, W2, dinv, H, n);
        k_aggregate<32, 0><<<ablk, B, 0, stream>>>(H, rpb, rpe, col, dinv, b2, A, n);
    }
    // ---- layer 3: 32 -> 16, relu ----
    {
        k_gemm_tiled<32, 16, 32><<<gblk, B, 0, stream>>>(A, W3, dinv, H, n);
        k_aggregate<16, 0><<<ablk, B, 0, stream>>>(H, rpb, rpe, col, dinv, b3, A, n);
    }
    // ---- layer 4: 16 -> 4, log_softmax ----
    {
        constexpr int NPW = 16;
        const int g4 = ((n + NPW - 1) / NPW + 3) / 4;
        k_gemm<16, 4, NPW><<<g4, B, 0, stream>>>(A, W4, dinv, H, n);
        k_aggregate<4, 2><<<ablk, B, 0, stream>>>(H, rpb, rpe, col, dinv, b4, out, n);
    }
}

// Round 10
// 409.114 us; speedup vs baseline: 2.3561x; 1.0662x over previous
//
#include <hip/hip_runtime.h>

#define N_NODES 100000
#define N_EDGES 3200000

// CSR sort geometry
#define BSH 8                        // 256 nodes per bucket
#define NB 391                       // ceil(100000/256)
#define G_SRT 256                    // blocks in hist/scatter pass
#define EPB ((N_EDGES + G_SRT - 1) / G_SRT)   // 12500 edges per block
#define HP 392                       // hist row pitch

// f32 -> bf16 round-to-nearest-even
__device__ __forceinline__ unsigned short f2bf(float f) {
    unsigned u = __float_as_uint(f);
    u = (u + 0x7FFFu + ((u >> 16) & 1u)) >> 16;
    return (unsigned short)u;
}
__device__ __forceinline__ float bf2f(unsigned short b) {
    return __uint_as_float(((unsigned)b) << 16);
}

// ======================= CSR build (one-pass multisplit, no global atomics) =======================

// per-block histogram over 391 dst-buckets
__global__ __launch_bounds__(256) void k_hist_blk(const int* __restrict__ ei,
                                                  int* __restrict__ hist, int e) {
    __shared__ int lh[NB];
    int b = (int)blockIdx.x, t = (int)threadIdx.x;
    for (int k = t; k < NB; k += 256) lh[k] = 0;
    __syncthreads();
    int i0 = b * EPB, i1 = i0 + EPB; if (i1 > e) i1 = e;
    for (int i = i0 + t; i < i1; i += 256) {
        int d = ei[e + i];
        if ((unsigned)d < (unsigned)N_NODES) atomicAdd(&lh[d >> BSH], 1);
    }
    __syncthreads();
    for (int k = t; k < NB; k += 256) hist[b * HP + k] = lh[k];
}

// per-bucket exclusive scan across blocks -> offs[bucket][block], totals
__global__ __launch_bounds__(256) void k_scan_col(const int* __restrict__ hist,
                                                  int* __restrict__ offs, int* __restrict__ tot) {
    __shared__ int sm[256];
    int k = (int)blockIdx.x, t = (int)threadIdx.x;
    int v = hist[t * HP + k];
    sm[t] = v;
    __syncthreads();
    for (int off = 1; off < 256; off <<= 1) {
        int x = (t >= off) ? sm[t - off] : 0;
        __syncthreads();
        sm[t] += x;
        __syncthreads();
    }
    offs[k * G_SRT + t] = sm[t] - v;
    if (t == 255) tot[k] = sm[255];
}

// scan bucket totals -> bBase[0..NB]
__global__ void k_scan_tot(const int* __restrict__ tot, int* __restrict__ bBase) {
    __shared__ int sm[512];
    int t = (int)threadIdx.x;
    int v = (t < NB) ? tot[t] : 0;
    sm[t] = v;
    __syncthreads();
    for (int off = 1; off < 512; off <<= 1) {
        int x = (t >= off) ? sm[t - off] : 0;
        __syncthreads();
        sm[t] += x;
        __syncthreads();
    }
    if (t < NB) bBase[t] = sm[t] - v;
    if (t == NB - 1) bBase[NB] = sm[t];
}

// block-local multisplit: LDS-rank + LDS-staged tile, then contiguous segment copies.
__global__ __launch_bounds__(256) void k_scatter_srt(const int* __restrict__ ei,
                                                     const int* __restrict__ offs,
                                                     const int* __restrict__ bBase,
                                                     unsigned* __restrict__ bins, int e) {
    __shared__ unsigned sbuf[EPB];                 // 50 KB staging
    __shared__ int lh[NB], lcur[NB], gdst[NB];
    __shared__ int sA[NB], sBf[NB];
    int b = (int)blockIdx.x, t = (int)threadIdx.x;
    int i0 = b * EPB, i1 = i0 + EPB; if (i1 > e) i1 = e;

    for (int k = t; k < NB; k += 256) lh[k] = 0;
    __syncthreads();
    for (int i = i0 + t; i < i1; i += 256) {
        int d = ei[e + i];
        if ((unsigned)d < (unsigned)N_NODES) atomicAdd(&lh[d >> BSH], 1);
    }
    __syncthreads();

    int* cur = sA; int* nxt = sBf;
    for (int k = t; k < NB; k += 256) cur[k] = lh[k];
    __syncthreads();
    for (int off = 1; off < NB; off <<= 1) {
        for (int k = t; k < NB; k += 256) nxt[k] = cur[k] + (k >= off ? cur[k - off] : 0);
        __syncthreads();
        int* tmp = cur; cur = nxt; nxt = tmp;
    }
    for (int k = t; k < NB; k += 256) {
        lcur[k] = cur[k] - lh[k];                       // local exclusive base
        gdst[k] = bBase[k] + offs[k * G_SRT + b];       // global dest base
    }
    __syncthreads();

    for (int i = i0 + t; i < i1; i += 256) {
        int s = ei[i];
        int d = ei[e + i];
        if ((unsigned)s >= (unsigned)N_NODES || (unsigned)d >= (unsigned)N_NODES) continue;
        int k = d >> BSH;
        int p = atomicAdd(&lcur[k], 1);
        sbuf[p] = ((unsigned)(d & 255) << 17) | (unsigned)s;
    }
    __syncthreads();

    int wv = t >> 6, ln = t & 63;
    for (int k = wv; k < NB; k += 4) {
        int cnt = lh[k];
        int src0 = lcur[k] - cnt;
        int dst0 = gdst[k];
        for (int j = ln; j < cnt; j += 64) bins[dst0 + j] = sbuf[src0 + j];
    }
}

// one block per bucket: LDS hist -> rp/dinv, then LDS-cursor scatter of col
__global__ __launch_bounds__(256) void k_bucket(const unsigned* __restrict__ bins,
                                                const int* __restrict__ bBase,
                                                int* __restrict__ rpb, int* __restrict__ rpe,
                                                float* __restrict__ dinv,
                                                int* __restrict__ col, int n) {
    int b = (int)blockIdx.x;
    int t = (int)threadIdx.x;
    int base = bBase[b], next = bBase[b + 1];
    __shared__ int lcnt[256], lsc[256], lcur[256];
    lcnt[t] = 0;
    __syncthreads();
    for (int i = base + t; i < next; i += 256) atomicAdd(&lcnt[bins[i] >> 17], 1);
    __syncthreads();
    int c = lcnt[t];
    lsc[t] = c;
    __syncthreads();
    for (int off = 1; off < 256; off <<= 1) {
        int x = (t >= off) ? lsc[t - off] : 0;
        __syncthreads();
        lsc[t] += x;
        __syncthreads();
    }
    int excl = lsc[t] - c;
    int v = (b << BSH) + t;
    if (v < n) {
        rpb[v] = base + excl;
        rpe[v] = base + excl + c;
        dinv[v] = rsqrtf((float)(c + 1));  // +1 self-loop
    }
    lcur[t] = excl;
    __syncthreads();
    for (int i = base + t; i < next; i += 256) {
        unsigned ent = bins[i];
        int p = atomicAdd(&lcur[ent >> 17], 1);
        col[base + p] = (int)(ent & 0x1FFFFu);
    }
}

// ======================= dense: H(bf16) = (x @ W) * dinv[row] =======================
// LDS-tiled outer-product GEMM. Block = 64 nodes x OUT outs, 256 threads (16x16).
template <int K, int OUT, int BK>
__global__ __launch_bounds__(256) void k_gemm_tiled(const float* __restrict__ x,
                                                    const float* __restrict__ W,
                                                    const float* __restrict__ dinv,
                                                    unsigned short* __restrict__ h, int n) {
    constexpr int BM = 64;
    constexpr int TM = 4;
    constexpr int TN = OUT / 16;          // 4, 2, 1
    constexpr int PAD = 4;
    __shared__ float xs[BK][BM + PAD];
    __shared__ float ws[BK][OUT];

    int t = (int)threadIdx.x;
    int tm = t >> 4;
    int tn = t & 15;
    int m0 = blockIdx.x * BM;

    float acc[TM][TN];
#pragma unroll
    for (int i = 0; i < TM; ++i)
#pragma unroll
        for (int j = 0; j < TN; ++j) acc[i][j] = 0.0f;

    for (int kb = 0; kb < K; kb += BK) {
        if (kb) __syncthreads();
        constexpr int PER = (BM * BK) / (256 * 4);
#pragma unroll
        for (int f = 0; f < PER; ++f) {
            int flat = (f * 256 + t) * 4;
            int i = flat / BK;
            int j = flat % BK;
            int node = m0 + i;
            if (node >= n) node = n - 1;
            float4 v = *(const float4*)(x + (long long)node * K + kb + j);
            xs[j + 0][i] = v.x;
            xs[j + 1][i] = v.y;
            xs[j + 2][i] = v.z;
            xs[j + 3][i] = v.w;
        }
        constexpr int WE = BK * OUT / 4;
        for (int f = t; f < WE; f += 256) {
            int flat = f * 4;
            int k = flat / OUT;
            int o = flat % OUT;
            *(float4*)&ws[k][o] = *(const float4*)&W[(long long)(kb + k) * OUT + o];
        }
        __syncthreads();

#pragma unroll 8
        for (int k = 0; k < BK; ++k) {
            float4 av = *(const float4*)&xs[k][tm * 4];
            float a[TM] = {av.x, av.y, av.z, av.w};
            float b[TN];
            if constexpr (TN == 4) {
                float4 bv = *(const float4*)&ws[k][tn * 4];
                b[0] = bv.x; b[1] = bv.y; b[2] = bv.z; b[3] = bv.w;
            } else if constexpr (TN == 2) {
                float2 bv = *(const float2*)&ws[k][tn * 2];
                b[0] = bv.x; b[1] = bv.y;
            } else {
                b[0] = ws[k][tn];
            }
#pragma unroll
            for (int i = 0; i < TM; ++i)
#pragma unroll
                for (int j = 0; j < TN; ++j)
                    acc[i][j] = fmaf(a[i], b[j], acc[i][j]);
        }
    }

#pragma unroll
    for (int i = 0; i < TM; ++i) {
        int node = m0 + tm * 4 + i;
        if (node < n) {
            float di = dinv[node];
            unsigned short* hp = h + (long long)node * OUT + tn * TN;
            if constexpr (TN == 4) {
                ushort4 o4;
                o4.x = f2bf(acc[i][0] * di); o4.y = f2bf(acc[i][1] * di);
                o4.z = f2bf(acc[i][2] * di); o4.w = f2bf(acc[i][3] * di);
                *(ushort4*)hp = o4;
            } else if constexpr (TN == 2) {
                ushort2 o2;
                o2.x = f2bf(acc[i][0] * di); o2.y = f2bf(acc[i][1] * di);
                *(ushort2*)hp = o2;
            } else {
                hp[0] = f2bf(acc[i][0] * di);
            }
        }
    }
}

// per-wave gemm for the tiny final layer (K=16, OUT=4)
template <int K, int OUT, int NPW>
__global__ void k_gemm(const float* __restrict__ x, const float* __restrict__ W,
                       const float* __restrict__ dinv, unsigned short* __restrict__ h, int n) {
    constexpr int NS = 64 / OUT;
    constexpr int KC = (K < 64 * NS) ? K : 64 * NS;
    constexpr int JW = KC / NS;

    int tid = blockIdx.x * blockDim.x + threadIdx.x;
    int wid = __builtin_amdgcn_readfirstlane(tid >> 6);
    int lane = (int)threadIdx.x & 63;
    int o = lane % OUT;
    int s = lane / OUT;

    long long base = (long long)wid * NPW;
    if (base >= n) return;

    float acc[NPW];
#pragma unroll
    for (int m = 0; m < NPW; ++m) acc[m] = 0.0f;

    float w[JW];
    for (int kb = 0; kb < K; kb += KC) {
        const float* Wp = W + (long long)kb * OUT;
#pragma unroll
        for (int j = 0; j < JW; ++j) w[j] = Wp[j * 64 + lane];
#pragma unroll
        for (int m = 0; m < NPW; ++m) {
            const float* xr = x + (base + m) * K + kb;
#pragma unroll
            for (int j = 0; j < JW; ++j)
                acc[m] = fmaf(xr[j * NS + s], w[j], acc[m]);
        }
    }

#pragma unroll
    for (int m = 0; m < NPW; ++m)
#pragma unroll
        for (int off = OUT; off < 64; off <<= 1)
            acc[m] += __shfl_xor(acc[m], off, 64);

    if (s == 0) {
#pragma unroll
        for (int m = 0; m < NPW; ++m) {
            long long v = base + m;
            if (v < n) h[v * OUT + o] = f2bf(acc[m] * dinv[v]);
        }
    }
}

// ======================= sparse aggregate (bf16 gather, f32 accumulate) =======================
// lane = (edge-group eg, quad o4): LPR = D/4 lanes read one h row (8 B ushort4);
// EG = 64/LPR edges in flight per issue. MODE: 0 = relu, 2 = log_softmax (D==4)
template <int D, int MODE>
__global__ void k_aggregate(const unsigned short* __restrict__ h, const int* __restrict__ rpb,
                            const int* __restrict__ rpe, const int* __restrict__ col,
                            const float* __restrict__ dinv, const float* __restrict__ b,
                            float* __restrict__ out, int n) {
    constexpr int LPR = D / 4;
    constexpr int EG = 64 / LPR;

    int v = (int)((blockIdx.x * blockDim.x + threadIdx.x) >> 6);
    if (v >= n) return;
    int lane = (int)threadIdx.x & 63;
    int eg = lane / LPR;
    int o4 = lane % LPR;

    int beg = rpb[v], end = rpe[v];

    float4 acc = make_float4(0.f, 0.f, 0.f, 0.f);
    for (int i = beg + eg; i < end; i += EG) {
        int s = col[i];
        ushort4 hv = *(const ushort4*)(h + (long long)s * D + o4 * 4);
        acc.x += bf2f(hv.x); acc.y += bf2f(hv.y);
        acc.z += bf2f(hv.z); acc.w += bf2f(hv.w);
    }

#pragma unroll
    for (int off = LPR; off < 64; off <<= 1) {
        acc.x += __shfl_xor(acc.x, off, 64);
        acc.y += __shfl_xor(acc.y, off, 64);
        acc.z += __shfl_xor(acc.z, off, 64);
        acc.w += __shfl_xor(acc.w, off, 64);
    }

    if (lane < LPR) {
        ushort4 sv = *(const ushort4*)(h + (long long)v * D + o4 * 4);
        float4 bb = *(const float4*)(b + o4 * 4);
        float di = dinv[v];
        float4 val;
        val.x = di * (acc.x + bf2f(sv.x)) + bb.x;
        val.y = di * (acc.y + bf2f(sv.y)) + bb.y;
        val.z = di * (acc.z + bf2f(sv.z)) + bb.z;
        val.w = di * (acc.w + bf2f(sv.w)) + bb.w;

        if (MODE == 0) {
            val.x = fmaxf(val.x, 0.f); val.y = fmaxf(val.y, 0.f);
            val.z = fmaxf(val.z, 0.f); val.w = fmaxf(val.w, 0.f);
            *(float4*)(out + (long long)v * D + o4 * 4) = val;
        } else {
            float m = fmaxf(fmaxf(val.x, val.y), fmaxf(val.z, val.w));
            float s0 = __expf(val.x - m) + __expf(val.y - m) +
                       __expf(val.z - m) + __expf(val.w - m);
            float ls = m + __logf(s0);
            *(float4*)(out + (long long)v * 4) =
                make_float4(val.x - ls, val.y - ls, val.z - ls, val.w - ls);
        }
    }
}

// ======================= launch =======================

extern "C" void kernel_launch(void* const* d_in, const int* in_sizes, int n_in,
                              void* d_out, int out_size, void* d_ws, size_t ws_size,
                              hipStream_t stream) {
    const float* x = (const float*)d_in[0];
    const int* ei = (const int*)d_in[1];  // int32 [2, E]
    const float* W1 = (const float*)d_in[2];
    const float* b1 = (const float*)d_in[3];
    const float* W2 = (const float*)d_in[4];
    const float* b2 = (const float*)d_in[5];
    const float* W3 = (const float*)d_in[6];
    const float* b3 = (const float*)d_in[7];
    const float* W4 = (const float*)d_in[8];
    const float* b4 = (const float*)d_in[9];
    float* out = (float*)d_out;

    const int n = N_NODES;
    const int e = N_EDGES;
    const int B = 256;

    char* ws = (char*)d_ws;
    size_t off = 0;
    auto alloc = [&](size_t bytes) {
        void* p = ws + off;
        off += (bytes + 255) & ~size_t(255);
        return p;
    };
    float* dinv = (float*)alloc((size_t)n * 4);
    int* rpb = (int*)alloc((size_t)n * 4);
    int* rpe = (int*)alloc((size_t)n * 4);
    int* hist = (int*)alloc((size_t)G_SRT * HP * 4);
    int* offs = (int*)alloc((size_t)NB * G_SRT * 4);
    int* tot = (int*)alloc((size_t)NB * 4);
    int* bBase = (int*)alloc((size_t)(NB + 1) * 4);
    unsigned* bins = (unsigned*)alloc((size_t)e * 4);
    int* col = (int*)alloc((size_t)e * 4);
    unsigned short* H = (unsigned short*)alloc((size_t)n * 64 * 2);  // bf16
    float* A = (float*)alloc((size_t)n * 64 * 4);

    // ---- CSR build (multisplit, no global atomics) ----
    k_hist_blk<<<G_SRT, B, 0, stream>>>(ei, hist, e);
    k_scan_col<<<NB, B, 0, stream>>>(hist, offs, tot);
    k_scan_tot<<<1, 512, 0, stream>>>(tot, bBase);
    k_scatter_srt<<<G_SRT, B, 0, stream>>>(ei, offs, bBase, bins, e);
    k_bucket<<<NB, B, 0, stream>>>(bins, bBase, rpb, rpe, dinv, col, n);

    const int gblk = (n + 63) / 64;   // tiled gemm blocks (BM=64)
    const int ablk = (n + 3) / 4;     // aggregate blocks (4 waves / block)

    // ---- layer 1: 256 -> 64, relu ----
    {
        k_gemm_tiled<256, 64, 64><<<gblk, B, 0, stream>>>(x, W1, dinv, H, n);
        k_aggregate<64, 0><<<ablk, B, 0, stream>>>(H, rpb, rpe, col, dinv, b1, A, n);
    }
    // ---- layer 2: 64 -> 32, relu ----
    {
        k_gemm_tiled<64, 32, 64><<<gblk, B, 0, stream>>>(A, W2, dinv, H, n);
        k_aggregate<32, 0><<<ablk, B, 0, stream>>>(H, rpb, rpe, col, dinv, b2, A, n);
    }
    // ---- layer 3: 32 -> 16, relu ----
    {
        k_gemm_tiled<32, 16, 32><<<gblk, B, 0, stream>>>(A, W3, dinv, H, n);
        k_aggregate<16, 0><<<ablk, B, 0, stream>>>(H, rpb, rpe, col, dinv, b3, A, n);
    }
    // ---- layer 4: 16 -> 4, log_softmax ----
    {
        constexpr int NPW = 16;
        const int g4 = ((n + NPW - 1) / NPW + 3) / 4;
        k_gemm<16, 4, NPW><<<g4, B, 0, stream>>>(A, W4, dinv, H, n);
        k_aggregate<4, 2><<<ablk, B, 0, stream>>>(H, rpb, rpe, col, dinv, b4, out, n);
    }
}

// Round 11
// 374.501 us; speedup vs baseline: 2.5739x; 1.0924x over previous
//
#include <hip/hip_runtime.h>

#define N_NODES 100000
#define N_EDGES 3200000

// CSR sort geometry
#define BSH 8                        // 256 nodes per bucket
#define NB 391                       // ceil(100000/256)
#define G_SRT 256                    // blocks in hist/scatter pass
#define EPB ((N_EDGES + G_SRT - 1) / G_SRT)   // 12500 edges per block
#define HP 392                       // hist row pitch

// f32 -> bf16 round-to-nearest-even
__device__ __forceinline__ unsigned short f2bf(float f) {
    unsigned u = __float_as_uint(f);
    u = (u + 0x7FFFu + ((u >> 16) & 1u)) >> 16;
    return (unsigned short)u;
}
__device__ __forceinline__ float bf2f(unsigned short b) {
    return __uint_as_float(((unsigned)b) << 16);
}
// unpack packed pair of bf16 from one u32 (memory order: lo = first element)
__device__ __forceinline__ float bfp_lo(unsigned u) { return __uint_as_float(u << 16); }
__device__ __forceinline__ float bfp_hi(unsigned u) { return __uint_as_float(u & 0xFFFF0000u); }

// ======================= CSR build (one-pass multisplit, no global atomics) =======================

// per-block histogram over 391 dst-buckets
__global__ __launch_bounds__(256) void k_hist_blk(const int* __restrict__ ei,
                                                  int* __restrict__ hist, int e) {
    __shared__ int lh[NB];
    int b = (int)blockIdx.x, t = (int)threadIdx.x;
    for (int k = t; k < NB; k += 256) lh[k] = 0;
    __syncthreads();
    int i0 = b * EPB, i1 = i0 + EPB; if (i1 > e) i1 = e;
    for (int i = i0 + t; i < i1; i += 256) {
        int d = ei[e + i];
        if ((unsigned)d < (unsigned)N_NODES) atomicAdd(&lh[d >> BSH], 1);
    }
    __syncthreads();
    for (int k = t; k < NB; k += 256) hist[b * HP + k] = lh[k];
}

// per-bucket exclusive scan across blocks -> offs[bucket][block], totals
__global__ __launch_bounds__(256) void k_scan_col(const int* __restrict__ hist,
                                                  int* __restrict__ offs, int* __restrict__ tot) {
    __shared__ int sm[256];
    int k = (int)blockIdx.x, t = (int)threadIdx.x;
    int v = hist[t * HP + k];
    sm[t] = v;
    __syncthreads();
    for (int off = 1; off < 256; off <<= 1) {
        int x = (t >= off) ? sm[t - off] : 0;
        __syncthreads();
        sm[t] += x;
        __syncthreads();
    }
    offs[k * G_SRT + t] = sm[t] - v;
    if (t == 255) tot[k] = sm[255];
}

// scan bucket totals -> bBase[0..NB]
__global__ void k_scan_tot(const int* __restrict__ tot, int* __restrict__ bBase) {
    __shared__ int sm[512];
    int t = (int)threadIdx.x;
    int v = (t < NB) ? tot[t] : 0;
    sm[t] = v;
    __syncthreads();
    for (int off = 1; off < 512; off <<= 1) {
        int x = (t >= off) ? sm[t - off] : 0;
        __syncthreads();
        sm[t] += x;
        __syncthreads();
    }
    if (t < NB) bBase[t] = sm[t] - v;
    if (t == NB - 1) bBase[NB] = sm[t];
}

// block-local multisplit: LDS-rank + LDS-staged tile, then contiguous segment copies.
__global__ __launch_bounds__(256) void k_scatter_srt(const int* __restrict__ ei,
                                                     const int* __restrict__ offs,
                                                     const int* __restrict__ bBase,
                                                     unsigned* __restrict__ bins, int e) {
    __shared__ unsigned sbuf[EPB];                 // 50 KB staging
    __shared__ int lh[NB], lcur[NB], gdst[NB];
    __shared__ int sA[NB], sBf[NB];
    int b = (int)blockIdx.x, t = (int)threadIdx.x;
    int i0 = b * EPB, i1 = i0 + EPB; if (i1 > e) i1 = e;

    for (int k = t; k < NB; k += 256) lh[k] = 0;
    __syncthreads();
    for (int i = i0 + t; i < i1; i += 256) {
        int d = ei[e + i];
        if ((unsigned)d < (unsigned)N_NODES) atomicAdd(&lh[d >> BSH], 1);
    }
    __syncthreads();

    int* cur = sA; int* nxt = sBf;
    for (int k = t; k < NB; k += 256) cur[k] = lh[k];
    __syncthreads();
    for (int off = 1; off < NB; off <<= 1) {
        for (int k = t; k < NB; k += 256) nxt[k] = cur[k] + (k >= off ? cur[k - off] : 0);
        __syncthreads();
        int* tmp = cur; cur = nxt; nxt = tmp;
    }
    for (int k = t; k < NB; k += 256) {
        lcur[k] = cur[k] - lh[k];                       // local exclusive base
        gdst[k] = bBase[k] + offs[k * G_SRT + b];       // global dest base
    }
    __syncthreads();

    for (int i = i0 + t; i < i1; i += 256) {
        int s = ei[i];
        int d = ei[e + i];
        if ((unsigned)s >= (unsigned)N_NODES || (unsigned)d >= (unsigned)N_NODES) continue;
        int k = d >> BSH;
        int p = atomicAdd(&lcur[k], 1);
        sbuf[p] = ((unsigned)(d & 255) << 17) | (unsigned)s;
    }
    __syncthreads();

    int wv = t >> 6, ln = t & 63;
    for (int k = wv; k < NB; k += 4) {
        int cnt = lh[k];
        int src0 = lcur[k] - cnt;
        int dst0 = gdst[k];
        for (int j = ln; j < cnt; j += 64) bins[dst0 + j] = sbuf[src0 + j];
    }
}

// one block per bucket: LDS hist -> rp/dinv, then LDS-cursor scatter of col
__global__ __launch_bounds__(256) void k_bucket(const unsigned* __restrict__ bins,
                                                const int* __restrict__ bBase,
                                                int* __restrict__ rpb, int* __restrict__ rpe,
                                                float* __restrict__ dinv,
                                                int* __restrict__ col, int n) {
    int b = (int)blockIdx.x;
    int t = (int)threadIdx.x;
    int base = bBase[b], next = bBase[b + 1];
    __shared__ int lcnt[256], lsc[256], lcur[256];
    lcnt[t] = 0;
    __syncthreads();
    for (int i = base + t; i < next; i += 256) atomicAdd(&lcnt[bins[i] >> 17], 1);
    __syncthreads();
    int c = lcnt[t];
    lsc[t] = c;
    __syncthreads();
    for (int off = 1; off < 256; off <<= 1) {
        int x = (t >= off) ? lsc[t - off] : 0;
        __syncthreads();
        lsc[t] += x;
        __syncthreads();
    }
    int excl = lsc[t] - c;
    int v = (b << BSH) + t;
    if (v < n) {
        rpb[v] = base + excl;
        rpe[v] = base + excl + c;
        dinv[v] = rsqrtf((float)(c + 1));  // +1 self-loop
    }
    lcur[t] = excl;
    __syncthreads();
    for (int i = base + t; i < next; i += 256) {
        unsigned ent = bins[i];
        int p = atomicAdd(&lcur[ent >> 17], 1);
        col[base + p] = (int)(ent & 0x1FFFFu);
    }
}

// ======================= dense: H(bf16) = (x @ W) * dinv[row] =======================
// LDS-tiled outer-product GEMM. Block = 64 nodes x OUT outs, 256 threads (16x16).
template <int K, int OUT, int BK>
__global__ __launch_bounds__(256) void k_gemm_tiled(const float* __restrict__ x,
                                                    const float* __restrict__ W,
                                                    const float* __restrict__ dinv,
                                                    unsigned short* __restrict__ h, int n) {
    constexpr int BM = 64;
    constexpr int TM = 4;
    constexpr int TN = OUT / 16;          // 4, 2, 1
    constexpr int PAD = 4;
    __shared__ float xs[BK][BM + PAD];
    __shared__ float ws[BK][OUT];

    int t = (int)threadIdx.x;
    int tm = t >> 4;
    int tn = t & 15;
    int m0 = blockIdx.x * BM;

    float acc[TM][TN];
#pragma unroll
    for (int i = 0; i < TM; ++i)
#pragma unroll
        for (int j = 0; j < TN; ++j) acc[i][j] = 0.0f;

    for (int kb = 0; kb < K; kb += BK) {
        if (kb) __syncthreads();
        constexpr int PER = (BM * BK) / (256 * 4);
#pragma unroll
        for (int f = 0; f < PER; ++f) {
            int flat = (f * 256 + t) * 4;
            int i = flat / BK;
            int j = flat % BK;
            int node = m0 + i;
            if (node >= n) node = n - 1;
            float4 v = *(const float4*)(x + (long long)node * K + kb + j);
            xs[j + 0][i] = v.x;
            xs[j + 1][i] = v.y;
            xs[j + 2][i] = v.z;
            xs[j + 3][i] = v.w;
        }
        constexpr int WE = BK * OUT / 4;
        for (int f = t; f < WE; f += 256) {
            int flat = f * 4;
            int k = flat / OUT;
            int o = flat % OUT;
            *(float4*)&ws[k][o] = *(const float4*)&W[(long long)(kb + k) * OUT + o];
        }
        __syncthreads();

#pragma unroll 8
        for (int k = 0; k < BK; ++k) {
            float4 av = *(const float4*)&xs[k][tm * 4];
            float a[TM] = {av.x, av.y, av.z, av.w};
            float b[TN];
            if constexpr (TN == 4) {
                float4 bv = *(const float4*)&ws[k][tn * 4];
                b[0] = bv.x; b[1] = bv.y; b[2] = bv.z; b[3] = bv.w;
            } else if constexpr (TN == 2) {
                float2 bv = *(const float2*)&ws[k][tn * 2];
                b[0] = bv.x; b[1] = bv.y;
            } else {
                b[0] = ws[k][tn];
            }
#pragma unroll
            for (int i = 0; i < TM; ++i)
#pragma unroll
                for (int j = 0; j < TN; ++j)
                    acc[i][j] = fmaf(a[i], b[j], acc[i][j]);
        }
    }

#pragma unroll
    for (int i = 0; i < TM; ++i) {
        int node = m0 + tm * 4 + i;
        if (node < n) {
            float di = dinv[node];
            unsigned short* hp = h + (long long)node * OUT + tn * TN;
            if constexpr (TN == 4) {
                ushort4 o4;
                o4.x = f2bf(acc[i][0] * di); o4.y = f2bf(acc[i][1] * di);
                o4.z = f2bf(acc[i][2] * di); o4.w = f2bf(acc[i][3] * di);
                *(ushort4*)hp = o4;
            } else if constexpr (TN == 2) {
                ushort2 o2;
                o2.x = f2bf(acc[i][0] * di); o2.y = f2bf(acc[i][1] * di);
                *(ushort2*)hp = o2;
            } else {
                hp[0] = f2bf(acc[i][0] * di);
            }
        }
    }
}

// per-wave gemm for the tiny final layer (K=16, OUT=4)
template <int K, int OUT, int NPW>
__global__ void k_gemm(const float* __restrict__ x, const float* __restrict__ W,
                       const float* __restrict__ dinv, unsigned short* __restrict__ h, int n) {
    constexpr int NS = 64 / OUT;
    constexpr int KC = (K < 64 * NS) ? K : 64 * NS;
    constexpr int JW = KC / NS;

    int tid = blockIdx.x * blockDim.x + threadIdx.x;
    int wid = __builtin_amdgcn_readfirstlane(tid >> 6);
    int lane = (int)threadIdx.x & 63;
    int o = lane % OUT;
    int s = lane / OUT;

    long long base = (long long)wid * NPW;
    if (base >= n) return;

    float acc[NPW];
#pragma unroll
    for (int m = 0; m < NPW; ++m) acc[m] = 0.0f;

    float w[JW];
    for (int kb = 0; kb < K; kb += KC) {
        const float* Wp = W + (long long)kb * OUT;
#pragma unroll
        for (int j = 0; j < JW; ++j) w[j] = Wp[j * 64 + lane];
#pragma unroll
        for (int m = 0; m < NPW; ++m) {
            const float* xr = x + (base + m) * K + kb;
#pragma unroll
            for (int j = 0; j < JW; ++j)
                acc[m] = fmaf(xr[j * NS + s], w[j], acc[m]);
        }
    }

#pragma unroll
    for (int m = 0; m < NPW; ++m)
#pragma unroll
        for (int off = OUT; off < 64; off <<= 1)
            acc[m] += __shfl_xor(acc[m], off, 64);

    if (s == 0) {
#pragma unroll
        for (int m = 0; m < NPW; ++m) {
            long long v = base + m;
            if (v < n) h[v * OUT + o] = f2bf(acc[m] * dinv[v]);
        }
    }
}

// ======================= sparse aggregate (bf16 gather, f32 accumulate) =======================
// D >= 16: lane = (edge-group eg, octet o8): LPR = D/8 lanes read one h row as
// uint4 (16 B = 8 bf16); EG = 64/LPR edges in flight per issue.
// D == 4: one edge per lane (8 B row). MODE: 0 = relu, 2 = log_softmax (D==4)
template <int D, int MODE>
__global__ void k_aggregate(const unsigned short* __restrict__ h, const int* __restrict__ rpb,
                            const int* __restrict__ rpe, const int* __restrict__ col,
                            const float* __restrict__ dinv, const float* __restrict__ b,
                            float* __restrict__ out, int n) {
    int v = (int)((blockIdx.x * blockDim.x + threadIdx.x) >> 6);
    if (v >= n) return;
    int lane = (int)threadIdx.x & 63;
    int beg = rpb[v], end = rpe[v];

    if constexpr (D >= 16) {
        constexpr int LPR = D / 8;   // lanes per row (8, 4, 2)
        constexpr int EG = 64 / LPR; // concurrent edges per wave (8, 16, 32)
        int eg = lane / LPR;
        int o8 = lane % LPR;

        float acc[8];
#pragma unroll
        for (int j = 0; j < 8; ++j) acc[j] = 0.0f;

        for (int i = beg + eg; i < end; i += EG) {
            int s = col[i];
            uint4 hv = *(const uint4*)(h + (long long)s * D + o8 * 8);
            acc[0] += bfp_lo(hv.x); acc[1] += bfp_hi(hv.x);
            acc[2] += bfp_lo(hv.y); acc[3] += bfp_hi(hv.y);
            acc[4] += bfp_lo(hv.z); acc[5] += bfp_hi(hv.z);
            acc[6] += bfp_lo(hv.w); acc[7] += bfp_hi(hv.w);
        }

#pragma unroll
        for (int off = LPR; off < 64; off <<= 1)
#pragma unroll
            for (int j = 0; j < 8; ++j) acc[j] += __shfl_xor(acc[j], off, 64);

        if (lane < LPR) {
            uint4 sv = *(const uint4*)(h + (long long)v * D + o8 * 8);
            float self[8] = {bfp_lo(sv.x), bfp_hi(sv.x), bfp_lo(sv.y), bfp_hi(sv.y),
                             bfp_lo(sv.z), bfp_hi(sv.z), bfp_lo(sv.w), bfp_hi(sv.w)};
            float4 b0 = *(const float4*)(b + o8 * 8);
            float4 b1 = *(const float4*)(b + o8 * 8 + 4);
            float bb[8] = {b0.x, b0.y, b0.z, b0.w, b1.x, b1.y, b1.z, b1.w};
            float di = dinv[v];
            float val[8];
#pragma unroll
            for (int j = 0; j < 8; ++j) {
                val[j] = di * (acc[j] + self[j]) + bb[j];
                val[j] = fmaxf(val[j], 0.0f);  // MODE==0 for all D>=16 layers
            }
            float* op = out + (long long)v * D + o8 * 8;
            *(float4*)op = make_float4(val[0], val[1], val[2], val[3]);
            *(float4*)(op + 4) = make_float4(val[4], val[5], val[6], val[7]);
        }
    } else {
        // D == 4: one edge per lane, 8 B row
        float4 acc = make_float4(0.f, 0.f, 0.f, 0.f);
        for (int i = beg + lane; i < end; i += 64) {
            int s = col[i];
            ushort4 hv = *(const ushort4*)(h + (long long)s * D);
            acc.x += bf2f(hv.x); acc.y += bf2f(hv.y);
            acc.z += bf2f(hv.z); acc.w += bf2f(hv.w);
        }
#pragma unroll
        for (int off = 1; off < 64; off <<= 1) {
            acc.x += __shfl_xor(acc.x, off, 64);
            acc.y += __shfl_xor(acc.y, off, 64);
            acc.z += __shfl_xor(acc.z, off, 64);
            acc.w += __shfl_xor(acc.w, off, 64);
        }
        if (lane == 0) {
            ushort4 sv = *(const ushort4*)(h + (long long)v * D);
            float4 bb = *(const float4*)b;
            float di = dinv[v];
            float x0 = di * (acc.x + bf2f(sv.x)) + bb.x;
            float x1 = di * (acc.y + bf2f(sv.y)) + bb.y;
            float x2 = di * (acc.z + bf2f(sv.z)) + bb.z;
            float x3 = di * (acc.w + bf2f(sv.w)) + bb.w;
            if (MODE == 0) {
                *(float4*)(out + (long long)v * 4) = make_float4(
                    fmaxf(x0, 0.f), fmaxf(x1, 0.f), fmaxf(x2, 0.f), fmaxf(x3, 0.f));
            } else {
                float m = fmaxf(fmaxf(x0, x1), fmaxf(x2, x3));
                float s0 = __expf(x0 - m) + __expf(x1 - m) + __expf(x2 - m) + __expf(x3 - m);
                float ls = m + __logf(s0);
                *(float4*)(out + (long long)v * 4) =
                    make_float4(x0 - ls, x1 - ls, x2 - ls, x3 - ls);
            }
        }
    }
}

// ======================= launch =======================

extern "C" void kernel_launch(void* const* d_in, const int* in_sizes, int n_in,
                              void* d_out, int out_size, void* d_ws, size_t ws_size,
                              hipStream_t stream) {
    const float* x = (const float*)d_in[0];
    const int* ei = (const int*)d_in[1];  // int32 [2, E]
    const float* W1 = (const float*)d_in[2];
    const float* b1 = (const float*)d_in[3];
    const float* W2 = (const float*)d_in[4];
    const float* b2 = (const float*)d_in[5];
    const float* W3 = (const float*)d_in[6];
    const float* b3 = (const float*)d_in[7];
    const float* W4 = (const float*)d_in[8];
    const float* b4 = (const float*)d_in[9];
    float* out = (float*)d_out;

    const int n = N_NODES;
    const int e = N_EDGES;
    const int B = 256;

    char* ws = (char*)d_ws;
    size_t off = 0;
    auto alloc = [&](size_t bytes) {
        void* p = ws + off;
        off += (bytes + 255) & ~size_t(255);
        return p;
    };
    float* dinv = (float*)alloc((size_t)n * 4);
    int* rpb = (int*)alloc((size_t)n * 4);
    int* rpe = (int*)alloc((size_t)n * 4);
    int* hist = (int*)alloc((size_t)G_SRT * HP * 4);
    int* offs = (int*)alloc((size_t)NB * G_SRT * 4);
    int* tot = (int*)alloc((size_t)NB * 4);
    int* bBase = (int*)alloc((size_t)(NB + 1) * 4);
    unsigned* bins = (unsigned*)alloc((size_t)e * 4);
    int* col = (int*)alloc((size_t)e * 4);
    unsigned short* H = (unsigned short*)alloc((size_t)n * 64 * 2);  // bf16
    float* A = (float*)alloc((size_t)n * 64 * 4);

    // ---- CSR build (multisplit, no global atomics) ----
    k_hist_blk<<<G_SRT, B, 0, stream>>>(ei, hist, e);
    k_scan_col<<<NB, B, 0, stream>>>(hist, offs, tot);
    k_scan_tot<<<1, 512, 0, stream>>>(tot, bBase);
    k_scatter_srt<<<G_SRT, B, 0, stream>>>(ei, offs, bBase, bins, e);
    k_bucket<<<NB, B, 0, stream>>>(bins, bBase, rpb, rpe, dinv, col, n);

    const int gblk = (n + 63) / 64;   // tiled gemm blocks (BM=64)
    const int ablk = (n + 3) / 4;     // aggregate blocks (4 waves / block)

    // ---- layer 1: 256 -> 64, relu ----
    {
        k_gemm_tiled<256, 64, 64><<<gblk, B, 0, stream>>>(x, W1, dinv, H, n);
        k_aggregate<64, 0><<<ablk, B, 0, stream>>>(H, rpb, rpe, col, dinv, b1, A, n);
    }
    // ---- layer 2: 64 -> 32, relu ----
    {
        k_gemm_tiled<64, 32, 64><<<gblk, B, 0, stream>>>(A, W2, dinv, H, n);
        k_aggregate<32, 0><<<ablk, B, 0, stream>>>(H, rpb, rpe, col, dinv, b2, A, n);
    }
    // ---- layer 3: 32 -> 16, relu ----
    {
        k_gemm_tiled<32, 16, 32><<<gblk, B, 0, stream>>>(A, W3, dinv, H, n);
        k_aggregate<16, 0><<<ablk, B, 0, stream>>>(H, rpb, rpe, col, dinv, b3, A, n);
    }
    // ---- layer 4: 16 -> 4, log_softmax ----
    {
        constexpr int NPW = 16;
        const int g4 = ((n + NPW - 1) / NPW + 3) / 4;
        k_gemm<16, 4, NPW><<<g4, B, 0, stream>>>(A, W4, dinv, H, n);
        k_aggregate<4, 2><<<ablk, B, 0, stream>>>(H, rpb, rpe, col, dinv, b4, out, n);
    }
}